// Round 2
// baseline (1725.900 us; speedup 1.0000x reference)
//
#include <hip/hip_runtime.h>
#include <math.h>

namespace {
constexpr int H = 128, W = 128, NB = 2;
constexpr int HW = H * W;
constexpr int NTHR = 256;
constexpr int NST  = 8;     // input channels staged per barrier
constexpr int DCN_CIN = 128, DCN_COUT = 64, DG = 16, CPG = 8;
}

// ---------------------------------------------------------------------------
// Generic 3x3 conv, stride 1, pad 1. Input = virtual concat of up to 3 sources.
// Block: TH x TW pixel tile x CC output channels; 256 threads.
// EPI: 0 = linear, 1 = leaky(0.1), 2 = fused offset/mask activation
//      (out planes 0..287: 10*tanh(v) + flipped flow;  288..431: sigmoid)
// ---------------------------------------------------------------------------
template<int CC, int TH, int TW, int EPI>
__global__ __launch_bounds__(NTHR) void conv3x3_k(
    const float* __restrict__ in0, int c0n,
    const float* __restrict__ in1, int c1n,
    const float* __restrict__ in2, int c2n,
    const float* __restrict__ wt, const float* __restrict__ bias,
    const float* __restrict__ flow1, const float* __restrict__ flow2,
    float* __restrict__ out, int Cin, int Cout)
{
  constexpr int RS  = NTHR / TW;      // tile rows covered per pass
  constexpr int PPT = TH / RS;        // pixels per thread
  constexpr int HHH = TH + 2, HWW = TW + 2;
  constexpr int HN  = HHH * HWW;
  constexpr int TX  = W / TW;

  __shared__ float s_in[NST][HHH][HWW];
  const int t    = threadIdx.x;
  const int tile = blockIdx.x;
  const int tx0  = (tile % TX) * TW;
  const int ty0  = (tile / TX) * TH;
  const int oc0  = blockIdx.y * CC;
  const int b    = blockIdx.z;
  const int lx   = t % TW;
  const int ly   = t / TW;            // 0..RS-1

  float acc[CC][PPT];
  #pragma unroll
  for (int o = 0; o < CC; ++o)
    #pragma unroll
    for (int p = 0; p < PPT; ++p) acc[o][p] = 0.f;

  for (int cb = 0; cb < Cin; cb += NST) {
    __syncthreads();
    #pragma unroll 1
    for (int i = 0; i < NST; ++i) {
      const int c = cb + i;
      if (c < Cin) {
        const float* src; int cc, cs;
        if (c < c0n)            { src = in0; cc = c;             cs = c0n; }
        else if (c < c0n + c1n) { src = in1; cc = c - c0n;       cs = c1n; }
        else                    { src = in2; cc = c - c0n - c1n; cs = c2n; }
        const float* sb = src + (b * cs + cc) * HW;
        for (int idx = t; idx < HN; idx += NTHR) {
          const int hy = idx / HWW, hx = idx - hy * HWW;
          const int gy = ty0 + hy - 1, gx = tx0 + hx - 1;
          float v = 0.f;
          if (gy >= 0 && gy < H && gx >= 0 && gx < W) v = sb[gy * W + gx];
          (&s_in[i][0][0])[idx] = v;
        }
      } else {
        for (int idx = t; idx < HN; idx += NTHR) (&s_in[i][0][0])[idx] = 0.f;
      }
    }
    __syncthreads();
    const int cmax = (Cin - cb < NST) ? (Cin - cb) : NST;
    #pragma unroll 1
    for (int i = 0; i < cmax; ++i) {
      float va[PPT][9];
      #pragma unroll
      for (int p = 0; p < PPT; ++p)
        #pragma unroll
        for (int dy = 0; dy < 3; ++dy)
          #pragma unroll
          for (int dx = 0; dx < 3; ++dx)
            va[p][dy * 3 + dx] = s_in[i][ly + p * RS + dy][lx + dx];
      const int c = cb + i;
      const float* wp = wt + (oc0 * Cin + c) * 9;
      #pragma unroll
      for (int o = 0; o < CC; ++o) {
        const float* wo = wp + o * Cin * 9;
        #pragma unroll
        for (int k = 0; k < 9; ++k) {
          const float wk = wo[k];
          #pragma unroll
          for (int p = 0; p < PPT; ++p)
            acc[o][p] = fmaf(va[p][k], wk, acc[o][p]);
        }
      }
    }
  }

  const int xo = tx0 + lx;
  // for EPI==2: preload the 8 possible flow addends (flow sel x yx x pixel)
  float fv[PPT][2][2];
  if (EPI == 2) {
    #pragma unroll
    for (int p = 0; p < PPT; ++p) {
      const int pix = (ty0 + ly + p * RS) * W + xo;
      fv[p][0][0] = flow1[(b * 2 + 1) * HW + pix];  // g<8,  y-offset += flow1.ch1
      fv[p][0][1] = flow1[(b * 2 + 0) * HW + pix];  // g<8,  x-offset += flow1.ch0
      fv[p][1][0] = flow2[(b * 2 + 1) * HW + pix];
      fv[p][1][1] = flow2[(b * 2 + 0) * HW + pix];
    }
  }

  #pragma unroll
  for (int o = 0; o < CC; ++o) {
    const int oc = oc0 + o;
    const float bz = bias[oc];
    #pragma unroll
    for (int p = 0; p < PPT; ++p) {
      float r = acc[o][p] + bz;
      if (EPI == 1) r = (r >= 0.f) ? r : 0.1f * r;
      if (EPI == 2) {
        if (oc < 288) {
          const int yx = oc & 1;
          const int g2 = ((oc >> 1) / 9 >= 8) ? 1 : 0;
          r = 10.f * tanhf(r) + fv[p][g2][yx];
        } else {
          r = 1.f / (1.f + expf(-r));
        }
      }
      const int y = ty0 + ly + p * RS;
      out[(b * Cout + oc) * HW + y * W + xo] = r;
    }
  }
}

// ---------------------------------------------------------------------------
// Modulated deformable conv. o4 holds POST-ACTIVATED offsets (flow added) and
// masks (sigmoid applied). Block: 16x16 pixel tile x CC output channels.
// ---------------------------------------------------------------------------
template<int CC>
__global__ __launch_bounds__(NTHR) void deform_k(
    const float* __restrict__ x,      // [B,128,H,W]
    const float* __restrict__ o4,     // [B,432,H,W] activated offset+mask
    const float* __restrict__ dw,     // [64,128,3,3]
    const float* __restrict__ db,     // [64]
    float* __restrict__ out)          // [B,64,H,W]
{
  const int t    = threadIdx.x;
  const int tile = blockIdx.x;        // 64 tiles (8x8 of 16x16)
  const int oc0  = blockIdx.y * CC;
  const int b    = blockIdx.z;
  const int lx   = t & 15, ly = t >> 4;
  const int hx   = (tile & 7) * 16 + lx;
  const int hy   = (tile >> 3) * 16 + ly;
  const int pix  = hy * W + hx;

  const float* ob = o4 + (b * 432) * HW + pix;
  const float* xb = x + (b * DCN_CIN) * HW;

  float acc[CC];
  #pragma unroll
  for (int o = 0; o < CC; ++o) acc[o] = 0.f;

  #pragma unroll 1
  for (int g = 0; g < DG; ++g) {
    float w00[9], w01[9], w10[9], w11[9];
    int   i00[9], i01[9], i10[9], i11[9];
    #pragma unroll
    for (int k = 0; k < 9; ++k) {
      const int cb = g * 9 + k;
      const float oy = ob[(2 * cb + 0) * HW];
      const float ox = ob[(2 * cb + 1) * HW];
      const float mk = ob[(288 + cb) * HW];
      const float py  = (float)(hy + k / 3 - 1) + oy;
      const float pxx = (float)(hx + k % 3 - 1) + ox;
      const float y0f = floorf(py), x0f = floorf(pxx);
      const float wy = py - y0f, wx = pxx - x0f;
      const int y0 = (int)y0f, x0 = (int)x0f;
      const bool vy0 = (y0 >= 0) && (y0 < H);
      const bool vy1 = (y0 + 1 >= 0) && (y0 + 1 < H);
      const bool vx0 = (x0 >= 0) && (x0 < W);
      const bool vx1 = (x0 + 1 >= 0) && (x0 + 1 < W);
      const int cy0 = min(max(y0, 0), H - 1);
      const int cy1 = min(max(y0 + 1, 0), H - 1);
      const int cx0 = min(max(x0, 0), W - 1);
      const int cx1 = min(max(x0 + 1, 0), W - 1);
      i00[k] = cy0 * W + cx0; i01[k] = cy0 * W + cx1;
      i10[k] = cy1 * W + cx0; i11[k] = cy1 * W + cx1;
      w00[k] = (vy0 && vx0) ? (1.f - wy) * (1.f - wx) * mk : 0.f;
      w01[k] = (vy0 && vx1) ? (1.f - wy) * wx * mk : 0.f;
      w10[k] = (vy1 && vx0) ? wy * (1.f - wx) * mk : 0.f;
      w11[k] = (vy1 && vx1) ? wy * wx * mk : 0.f;
    }

    #pragma unroll 1
    for (int c = 0; c < CPG; ++c) {
      const float* xc = xb + (g * CPG + c) * HW;
      float val[9];
      #pragma unroll
      for (int k = 0; k < 9; ++k)
        val[k] = w00[k] * xc[i00[k]] + w01[k] * xc[i01[k]]
               + w10[k] * xc[i10[k]] + w11[k] * xc[i11[k]];
      const float* wrow = dw + (g * CPG + c) * 9;
      #pragma unroll
      for (int o = 0; o < CC; ++o) {
        const float* wo = wrow + (oc0 + o) * (DCN_CIN * 9);
        float a = acc[o];
        #pragma unroll
        for (int k = 0; k < 9; ++k) a = fmaf(val[k], wo[k], a);
        acc[o] = a;
      }
    }
  }

  #pragma unroll
  for (int o = 0; o < CC; ++o)
    out[(b * DCN_COUT + oc0 + o) * HW + pix] = acc[o] + db[oc0 + o];
}

// ---------------------------------------------------------------------------
extern "C" void kernel_launch(void* const* d_in, const int* in_sizes, int n_in,
                              void* d_out, int out_size, void* d_ws, size_t ws_size,
                              hipStream_t stream) {
  const float* x     = (const float*)d_in[0];
  const float* ef    = (const float*)d_in[1];
  const float* fl1   = (const float*)d_in[2];
  const float* fl2   = (const float*)d_in[3];
  const float* w1    = (const float*)d_in[4];
  const float* b1    = (const float*)d_in[5];
  const float* w2    = (const float*)d_in[6];
  const float* b2    = (const float*)d_in[7];
  const float* w3    = (const float*)d_in[8];
  const float* b3    = (const float*)d_in[9];
  const float* w4    = (const float*)d_in[10];
  const float* b4    = (const float*)d_in[11];
  const float* dcn_w = (const float*)d_in[12];
  const float* dcn_b = (const float*)d_in[13];

  float* ws = (float*)d_ws;
  float* hA = ws;                       // [2,64,128,128]  = 2,097,152 f
  float* hB = ws + 2097152;             // [2,64,128,128]
  float* o4 = ws + 4194304;             // [2,432,128,128] = 14,155,776 f (activated)

  const dim3 blk(NTHR);
  // conv1: ef(192) ++ flow1(2) ++ flow2(2) -> 64, leaky.  16x16 tiles, 512 blocks.
  conv3x3_k<16, 16, 16, 1><<<dim3(64, 4, NB), blk, 0, stream>>>(
      ef, 192, fl1, 2, fl2, 2, w1, b1, nullptr, nullptr, hA, 196, 64);
  // conv2: 64 -> 64, leaky
  conv3x3_k<16, 16, 16, 1><<<dim3(64, 4, NB), blk, 0, stream>>>(
      hA, 64, nullptr, 0, nullptr, 0, w2, b2, nullptr, nullptr, hB, 64, 64);
  // conv3: 64 -> 64, leaky
  conv3x3_k<16, 16, 16, 1><<<dim3(64, 4, NB), blk, 0, stream>>>(
      hB, 64, nullptr, 0, nullptr, 0, w3, b3, nullptr, nullptr, hA, 64, 64);
  // conv4: 64 -> 432, fused offset/mask activation epilogue. 16x32 tiles.
  conv3x3_k<16, 16, 32, 2><<<dim3(32, 27, NB), blk, 0, stream>>>(
      hA, 64, nullptr, 0, nullptr, 0, w4, b4, fl1, fl2, o4, 64, 432);
  // deformable conv on activated offsets
  deform_k<16><<<dim3(64, 4, NB), blk, 0, stream>>>(x, o4, dcn_w, dcn_b,
                                                    (float*)d_out);
}